// Round 3
// baseline (541.785 us; speedup 1.0000x reference)
//
#include <hip/hip_runtime.h>
#include <cstdint>

// ---------- common helpers ----------

typedef __bf16 bf16x8 __attribute__((ext_vector_type(8)));
typedef float  f32x4  __attribute__((ext_vector_type(4)));
typedef unsigned short u16x8 __attribute__((ext_vector_type(8)));

__device__ __forceinline__ unsigned short f2b(float f) {
    union { float f; unsigned u; } v; v.f = f;
    unsigned r = v.u + 0x7FFFu + ((v.u >> 16) & 1u);   // RNE
    return (unsigned short)(r >> 16);
}

__device__ __forceinline__ float b2f(unsigned short u) {
    union { unsigned u; float f; } v; v.u = ((unsigned)u) << 16;
    return v.f;
}

__device__ __forceinline__ void async_copy16(void* lds, const void* g) {
    __builtin_amdgcn_global_load_lds(
        (const __attribute__((address_space(1))) unsigned int*)g,
        (__attribute__((address_space(3))) unsigned int*)lds,
        16, 0, 0);
}

// ---------- conversion kernels ----------

__global__ __launch_bounds__(256) void k_cvt(const float* __restrict__ in,
                                             unsigned short* __restrict__ out) {
    int i = blockIdx.x * 256 + threadIdx.x;
    float4 f = ((const float4*)in)[i];
    ushort4 o = make_ushort4(f2b(f.x), f2b(f.y), f2b(f.z), f2b(f.w));
    ((ushort4*)out)[i] = o;
}

// in: [R][C] fp32 row-major  ->  out: [C][R] bf16 (transposed)
__global__ __launch_bounds__(256) void k_transpose_cvt(const float* __restrict__ in,
                                                       unsigned short* __restrict__ out,
                                                       int R, int C) {
    __shared__ float tile[32][33];
    int bc = blockIdx.x * 32;
    int br = blockIdx.y * 32;
    int tx = threadIdx.x, ty = threadIdx.y;   // (32, 8)
    #pragma unroll
    for (int i = 0; i < 32; i += 8)
        tile[ty + i][tx] = in[(size_t)(br + ty + i) * C + bc + tx];
    __syncthreads();
    #pragma unroll
    for (int i = 0; i < 32; i += 8)
        out[(size_t)(bc + ty + i) * R + br + tx] = f2b(tile[tx][ty + i]);
}

// ---------- 256-thread 128x128 GEMM (m97-style) ----------
// C[M][N] = A[M][K] * B^T[N][K]
// MODE 1: +bias, store bf16
// MODE 2: store fp32 partial at Out + kz*pstride (split-K, no atomics)

template <int MODE>
__global__ __launch_bounds__(256)
void k_gemm(const unsigned short* __restrict__ A,
            const unsigned short* __restrict__ B,
            const float* __restrict__ bias,
            void* __restrict__ Out, int ldout,
            int lda, int ldb, int k_len, size_t pstride) {
    __shared__ __align__(16) unsigned short As[128 * 32];
    __shared__ __align__(16) unsigned short Bs[128 * 32];

    const int tid  = threadIdx.x;
    const int wave = tid >> 6;
    const int lane = tid & 63;
    const int quad = lane >> 4;
    const int l16  = lane & 15;
    const int wr   = wave >> 1;
    const int wc   = wave & 1;

    const int bn = blockIdx.x;
    const int bm = blockIdx.y;
    const int kz = blockIdx.z;

    const unsigned short* Ag = A + (size_t)(bm * 128) * lda + (size_t)kz * k_len;
    const unsigned short* Bg = B + (size_t)(bn * 128) * ldb + (size_t)kz * k_len;

    f32x4 acc[4][4];
    #pragma unroll
    for (int i = 0; i < 4; i++)
        #pragma unroll
        for (int j = 0; j < 4; j++)
            acc[i][j] = f32x4{0.f, 0.f, 0.f, 0.f};

    const int ch0 = wave * 128 + lane;
    const int ch1 = ch0 + 64;
    const int r0 = ch0 >> 2, c0 = ch0 & 3;
    const int r1 = ch1 >> 2, c1 = ch1 & 3;
    unsigned short* AsBase0 = &As[(wave * 128) * 8];
    unsigned short* AsBase1 = &As[(wave * 128 + 64) * 8];
    unsigned short* BsBase0 = &Bs[(wave * 128) * 8];
    unsigned short* BsBase1 = &Bs[(wave * 128 + 64) * 8];

    for (int k0 = 0; k0 < k_len; k0 += 32) {
        async_copy16(AsBase0, Ag + (size_t)r0 * lda + k0 + c0 * 8);
        async_copy16(AsBase1, Ag + (size_t)r1 * lda + k0 + c1 * 8);
        async_copy16(BsBase0, Bg + (size_t)r0 * ldb + k0 + c0 * 8);
        async_copy16(BsBase1, Bg + (size_t)r1 * ldb + k0 + c1 * 8);
        asm volatile("s_waitcnt vmcnt(0)" ::: "memory");
        __syncthreads();

        bf16x8 av[4], bv[4];
        #pragma unroll
        for (int i = 0; i < 4; i++)
            av[i] = *(const bf16x8*)&As[(wr * 64 + i * 16 + l16) * 32 + quad * 8];
        #pragma unroll
        for (int j = 0; j < 4; j++)
            bv[j] = *(const bf16x8*)&Bs[(wc * 64 + j * 16 + l16) * 32 + quad * 8];
        #pragma unroll
        for (int i = 0; i < 4; i++)
            #pragma unroll
            for (int j = 0; j < 4; j++)
                acc[i][j] = __builtin_amdgcn_mfma_f32_16x16x32_bf16(av[i], bv[j], acc[i][j], 0, 0, 0);
        __syncthreads();
    }

    #pragma unroll
    for (int i = 0; i < 4; i++) {
        int rbase = bm * 128 + wr * 64 + i * 16 + quad * 4;
        #pragma unroll
        for (int j = 0; j < 4; j++) {
            int col = bn * 128 + wc * 64 + j * 16 + l16;
            #pragma unroll
            for (int r = 0; r < 4; r++) {
                int row = rbase + r;
                float val = acc[i][j][r];
                if (MODE == 1) {
                    val += bias[col];
                    ((unsigned short*)Out)[(size_t)row * ldout + col] = f2b(val);
                } else {
                    ((float*)Out)[kz * pstride + (size_t)row * ldout + col] = val;
                }
            }
        }
    }
}

// ---------- reduce 2 fp32 partials + bias + tanh -> bf16 [8192][1024] ----------
__global__ __launch_bounds__(256)
void k_reduce_tanh(const float* __restrict__ P, const float* __restrict__ bias,
                   unsigned short* __restrict__ out) {
    int i = blockIdx.x * 256 + threadIdx.x;      // group of 4 elems
    int col = (i * 4) & 1023;
    float4 a = ((const float4*)P)[i];
    float4 b = ((const float4*)(P + (size_t)8192 * 1024))[i];
    float4 bs = ((const float4*)bias)[col >> 2];
    ushort4 o = make_ushort4(f2b(tanhf(a.x + b.x + bs.x)),
                             f2b(tanhf(a.y + b.y + bs.y)),
                             f2b(tanhf(a.z + b.z + bs.z)),
                             f2b(tanhf(a.w + b.w + bs.w)));
    ((ushort4*)out)[i] = o;
}

// ---------- sparsemax + gating: one WAVE per row, zero barriers ----------
__global__ __launch_bounds__(256)
void k_sparsemax(const unsigned short* __restrict__ a,
                 const unsigned short* __restrict__ xb,
                 unsigned short* __restrict__ wout) {
    const int wave = threadIdx.x >> 6;
    const int lane = threadIdx.x & 63;
    const int row = blockIdx.x * 4 + wave;

    const u16x8* ar = (const u16x8*)(a + (size_t)row * 4096);
    float v[64];
    #pragma unroll
    for (int j = 0; j < 8; j++) {
        u16x8 u = ar[lane + 64 * j];
        #pragma unroll
        for (int k = 0; k < 8; k++) v[j * 8 + k] = b2f(u[k]);
    }

    float m = v[0];
    #pragma unroll
    for (int i = 1; i < 64; i++) m = fmaxf(m, v[i]);
    #pragma unroll
    for (int off = 1; off < 64; off <<= 1) m = fmaxf(m, __shfl_xor(m, off));

    float lo = m - 1.0f, hi = m;
    #pragma unroll 1
    for (int it = 0; it < 18; ++it) {
        float mid = 0.5f * (lo + hi);
        float s = 0.f;
        #pragma unroll
        for (int i = 0; i < 64; i++) s += fmaxf(v[i] - mid, 0.f);
        #pragma unroll
        for (int off = 1; off < 64; off <<= 1) s += __shfl_xor(s, off);
        if (s > 1.0f) lo = mid; else hi = mid;
    }
    float tau = 0.5f * (lo + hi);

    const u16x8* xr = (const u16x8*)(xb + (size_t)row * 4096);
    u16x8* wr_ = (u16x8*)(wout + (size_t)row * 4096);
    #pragma unroll
    for (int j = 0; j < 8; j++) {
        u16x8 xv = xr[lane + 64 * j];
        u16x8 o;
        #pragma unroll
        for (int k = 0; k < 8; k++)
            o[k] = f2b(fmaxf(v[j * 8 + k] - tau, 0.f) * b2f(xv[k]));
        wr_[lane + 64 * j] = o;
    }
}

// ---------- final: out = relu(sum_p P[p] + bc1) @ Wc2 + bc2 ----------
__global__ __launch_bounds__(256)
void k_final(const float* __restrict__ P, const float* __restrict__ bc1,
             const float* __restrict__ Wc2, const float* __restrict__ bc2,
             float* __restrict__ out) {
    __shared__ float w2s[128 * 16];
    __shared__ float hs[4 * 128];
    const int tid = threadIdx.x;
    for (int i = tid; i < 2048; i += 256) w2s[i] = Wc2[i];

    // reduce 8 split-K partials + bias + relu into LDS (4 rows x 128)
    #pragma unroll
    for (int i = tid; i < 512; i += 256) {
        int r = i >> 7, c = i & 127;
        int row = blockIdx.x * 4 + r;
        float s = bc1[c];
        #pragma unroll
        for (int p = 0; p < 8; p++)
            s += P[((size_t)p * 8192 + row) * 128 + c];
        hs[i] = fmaxf(s, 0.f);
    }
    __syncthreads();

    const int wave = tid >> 6, lane = tid & 63;
    const int row = blockIdx.x * 4 + wave;
    const int c = lane & 15, hq = lane >> 4;
    float acc = 0.f;
    #pragma unroll
    for (int t = 0; t < 32; ++t) {
        int hidx = hq * 32 + t;
        acc += hs[wave * 128 + hidx] * w2s[hidx * 16 + c];
    }
    acc += __shfl_xor(acc, 16);
    acc += __shfl_xor(acc, 32);
    if (hq == 0) out[(size_t)row * 16 + c] = acc + bc2[c];
}

// ---------- launch ----------

extern "C" void kernel_launch(void* const* d_in, const int* in_sizes, int n_in,
                              void* d_out, int out_size, void* d_ws, size_t ws_size,
                              hipStream_t stream) {
    (void)in_sizes; (void)n_in; (void)out_size; (void)ws_size;
    const float* x   = (const float*)d_in[0];
    const float* W1  = (const float*)d_in[1];
    const float* b1  = (const float*)d_in[2];
    const float* W2  = (const float*)d_in[3];
    const float* b2  = (const float*)d_in[4];
    const float* Wc1 = (const float*)d_in[5];
    const float* bc1 = (const float*)d_in[6];
    const float* Wc2 = (const float*)d_in[7];
    const float* bc2 = (const float*)d_in[8];
    float* out = (float*)d_out;

    char* ws = (char*)d_ws;
    unsigned short* xb   = (unsigned short*)(ws);                  // 0..64 MB  bf16 x (later: weighted)
    unsigned short* W1t  = (unsigned short*)(ws + (64ll  << 20));  // 64..72
    unsigned short* Tb   = (unsigned short*)(ws + (72ll  << 20));  // 72..88
    unsigned short* W2t  = (unsigned short*)(ws + (88ll  << 20));  // 88..96
    float*          P1   = (float*)         (ws + (96ll  << 20));  // 96..160  GEMM1 partials (2x32MB)
    unsigned short* abf  = (unsigned short*)(ws + (96ll  << 20));  // 96..160  a bf16 (after P1 dead)
    float*          P3   = (float*)         (ws + (96ll  << 20));  // 96..128  GEMM3 partials (after abf dead)
    unsigned short* Wc1t = (unsigned short*)(ws + (160ll << 20));  // 160..161
    unsigned short* wb   = xb;

    dim3 tb(32, 8);
    k_cvt<<<32768, 256, 0, stream>>>(x, xb);
    k_transpose_cvt<<<dim3(1024 / 32, 4096 / 32), tb, 0, stream>>>(W1, W1t, 4096, 1024);
    k_transpose_cvt<<<dim3(4096 / 32, 1024 / 32), tb, 0, stream>>>(W2, W2t, 1024, 4096);
    k_transpose_cvt<<<dim3(128 / 32, 4096 / 32), tb, 0, stream>>>(Wc1, Wc1t, 4096, 128);

    // GEMM1 split-K=2: P1[kz] = x @ W1 (K-halves)
    k_gemm<2><<<dim3(8, 64, 2), 256, 0, stream>>>(xb, W1t, nullptr, P1, 1024,
                                                  4096, 4096, 2048, (size_t)8192 * 1024);
    // T = tanh(P1[0] + P1[1] + b1) -> bf16
    k_reduce_tanh<<<8192, 256, 0, stream>>>(P1, b1, Tb);
    // a = T @ W2 + b2 -> bf16  (P1 dead, abf aliases it)
    k_gemm<1><<<dim3(32, 64, 1), 256, 0, stream>>>(Tb, W2t, b2, abf, 4096,
                                                   1024, 1024, 1024, 0);
    // weighted = x * sparsemax(a) -> bf16 (in place over xb)
    k_sparsemax<<<2048, 256, 0, stream>>>(abf, xb, wb);
    // GEMM3 split-K=8: P3[kz] = weighted @ Wc1 (K-eighths)  (abf dead, P3 aliases)
    k_gemm<2><<<dim3(1, 64, 8), 256, 0, stream>>>(wb, Wc1t, nullptr, P3, 128,
                                                  4096, 4096, 512, (size_t)8192 * 128);
    // out = relu(sum P3 + bc1) @ Wc2 + bc2
    k_final<<<2048, 256, 0, stream>>>(P3, bc1, Wc2, bc2, out);
}

// Round 4
// 490.597 us; speedup vs baseline: 1.1043x; 1.1043x over previous
//
#include <hip/hip_runtime.h>
#include <cstdint>

// ---------- common helpers ----------

typedef __bf16 bf16x8 __attribute__((ext_vector_type(8)));
typedef float  f32x4  __attribute__((ext_vector_type(4)));
typedef unsigned short u16x8 __attribute__((ext_vector_type(8)));

__device__ __forceinline__ unsigned short f2b(float f) {
    union { float f; unsigned u; } v; v.f = f;
    unsigned r = v.u + 0x7FFFu + ((v.u >> 16) & 1u);   // RNE
    return (unsigned short)(r >> 16);
}

__device__ __forceinline__ float b2f(unsigned short u) {
    union { unsigned u; float f; } v; v.u = ((unsigned)u) << 16;
    return v.f;
}

__device__ __forceinline__ void async_copy16(void* lds, const void* g) {
    __builtin_amdgcn_global_load_lds(
        (const __attribute__((address_space(1))) unsigned int*)g,
        (__attribute__((address_space(3))) unsigned int*)lds,
        16, 0, 0);
}

// ---------- conversion kernels ----------

__global__ __launch_bounds__(256) void k_cvt(const float* __restrict__ in,
                                             unsigned short* __restrict__ out) {
    int i = blockIdx.x * 256 + threadIdx.x;
    float4 f = ((const float4*)in)[i];
    ushort4 o = make_ushort4(f2b(f.x), f2b(f.y), f2b(f.z), f2b(f.w));
    ((ushort4*)out)[i] = o;
}

// in: [R][C] fp32 row-major  ->  out: [C][R] bf16 (transposed)
__global__ __launch_bounds__(256) void k_transpose_cvt(const float* __restrict__ in,
                                                       unsigned short* __restrict__ out,
                                                       int R, int C) {
    __shared__ float tile[32][33];
    int bc = blockIdx.x * 32;
    int br = blockIdx.y * 32;
    int tx = threadIdx.x, ty = threadIdx.y;   // (32, 8)
    #pragma unroll
    for (int i = 0; i < 32; i += 8)
        tile[ty + i][tx] = in[(size_t)(br + ty + i) * C + bc + tx];
    __syncthreads();
    #pragma unroll
    for (int i = 0; i < 32; i += 8)
        out[(size_t)(bc + ty + i) * R + br + tx] = f2b(tile[tx][ty + i]);
}

// ---------- GEMM1: 512-thread 128x128 tile, bias+tanh -> bf16 ----------
// XCD-swizzled: bm % 8 == xcd so each A-tile is fetched by ONE XCD only.
// grid: 1-D, 512 blocks (8 bn x 64 bm).

__global__ __launch_bounds__(512, 4)
void k_gemm_tanh(const unsigned short* __restrict__ A,
                 const unsigned short* __restrict__ B,
                 const float* __restrict__ bias,
                 unsigned short* __restrict__ Out, int ldout,
                 int lda, int ldb, int k_len) {
    __shared__ __align__(16) unsigned short As[128 * 32];
    __shared__ __align__(16) unsigned short Bs[128 * 32];

    const int tid  = threadIdx.x;
    const int wave = tid >> 6;      // 0..7
    const int lane = tid & 63;
    const int quad = lane >> 4;
    const int l16  = lane & 15;
    const int wr   = wave >> 2;     // 0..1 : 64-row half
    const int wc   = wave & 3;      // 0..3 : 32-col quarter

    // XCD swizzle: bid % 8 ~ XCD id. bn fastest within an XCD.
    const int bid = blockIdx.x;
    const int xcd = bid & 7;
    const int lid = bid >> 3;           // 0..63
    const int bn  = lid & 7;            // 0..7
    const int bm  = (lid >> 3) * 8 + xcd;   // bm % 8 == xcd

    const unsigned short* Ag = A + (size_t)(bm * 128) * lda;
    const unsigned short* Bg = B + (size_t)(bn * 128) * ldb;

    f32x4 acc[4][2];
    #pragma unroll
    for (int i = 0; i < 4; i++)
        #pragma unroll
        for (int j = 0; j < 2; j++)
            acc[i][j] = f32x4{0.f, 0.f, 0.f, 0.f};

    const int ch = wave * 64 + lane;
    const int sr = ch >> 2, sc = ch & 3;
    unsigned short* AsBase = &As[(wave * 64) * 8];
    unsigned short* BsBase = &Bs[(wave * 64) * 8];

    for (int k0 = 0; k0 < k_len; k0 += 32) {
        async_copy16(AsBase, Ag + (size_t)sr * lda + k0 + sc * 8);
        async_copy16(BsBase, Bg + (size_t)sr * ldb + k0 + sc * 8);
        asm volatile("s_waitcnt vmcnt(0)" ::: "memory");
        __syncthreads();

        bf16x8 av[4], bv[2];
        #pragma unroll
        for (int i = 0; i < 4; i++)
            av[i] = *(const bf16x8*)&As[(wr * 64 + i * 16 + l16) * 32 + quad * 8];
        #pragma unroll
        for (int j = 0; j < 2; j++)
            bv[j] = *(const bf16x8*)&Bs[(wc * 32 + j * 16 + l16) * 32 + quad * 8];
        #pragma unroll
        for (int i = 0; i < 4; i++)
            #pragma unroll
            for (int j = 0; j < 2; j++)
                acc[i][j] = __builtin_amdgcn_mfma_f32_16x16x32_bf16(av[i], bv[j], acc[i][j], 0, 0, 0);
        __syncthreads();
    }

    #pragma unroll
    for (int i = 0; i < 4; i++) {
        int rbase = bm * 128 + wr * 64 + i * 16 + quad * 4;
        #pragma unroll
        for (int j = 0; j < 2; j++) {
            int col = bn * 128 + wc * 32 + j * 16 + l16;
            float bc = bias[col];
            #pragma unroll
            for (int r = 0; r < 4; r++)
                Out[(size_t)(rbase + r) * ldout + col] = f2b(tanhf(acc[i][j][r] + bc));
        }
    }
}

// ---------- 256-thread 128x128 GEMM (m97-style) ----------
// MODE 1: +bias, store bf16, XCD-swizzled 1-D grid (LBN = log2(#bn tiles))
// MODE 2: store fp32 partial at Out + kz*pstride (split-K, 3-D grid, no swizzle)

template <int MODE, int LBN>
__global__ __launch_bounds__(256)
void k_gemm(const unsigned short* __restrict__ A,
            const unsigned short* __restrict__ B,
            const float* __restrict__ bias,
            void* __restrict__ Out, int ldout,
            int lda, int ldb, int k_len, size_t pstride) {
    __shared__ __align__(16) unsigned short As[128 * 32];
    __shared__ __align__(16) unsigned short Bs[128 * 32];

    const int tid  = threadIdx.x;
    const int wave = tid >> 6;
    const int lane = tid & 63;
    const int quad = lane >> 4;
    const int l16  = lane & 15;
    const int wr   = wave >> 1;
    const int wc   = wave & 1;

    int bn, bm, kz;
    if (LBN >= 0) {
        const int bid = blockIdx.x;
        const int xcd = bid & 7;
        const int lid = bid >> 3;
        bn = lid & ((1 << LBN) - 1);
        bm = (lid >> LBN) * 8 + xcd;    // bm % 8 == xcd
        kz = 0;
    } else {
        bn = blockIdx.x; bm = blockIdx.y; kz = blockIdx.z;
    }

    const unsigned short* Ag = A + (size_t)(bm * 128) * lda + (size_t)kz * k_len;
    const unsigned short* Bg = B + (size_t)(bn * 128) * ldb + (size_t)kz * k_len;

    f32x4 acc[4][4];
    #pragma unroll
    for (int i = 0; i < 4; i++)
        #pragma unroll
        for (int j = 0; j < 4; j++)
            acc[i][j] = f32x4{0.f, 0.f, 0.f, 0.f};

    const int ch0 = wave * 128 + lane;
    const int ch1 = ch0 + 64;
    const int r0 = ch0 >> 2, c0 = ch0 & 3;
    const int r1 = ch1 >> 2, c1 = ch1 & 3;
    unsigned short* AsBase0 = &As[(wave * 128) * 8];
    unsigned short* AsBase1 = &As[(wave * 128 + 64) * 8];
    unsigned short* BsBase0 = &Bs[(wave * 128) * 8];
    unsigned short* BsBase1 = &Bs[(wave * 128 + 64) * 8];

    for (int k0 = 0; k0 < k_len; k0 += 32) {
        async_copy16(AsBase0, Ag + (size_t)r0 * lda + k0 + c0 * 8);
        async_copy16(AsBase1, Ag + (size_t)r1 * lda + k0 + c1 * 8);
        async_copy16(BsBase0, Bg + (size_t)r0 * ldb + k0 + c0 * 8);
        async_copy16(BsBase1, Bg + (size_t)r1 * ldb + k0 + c1 * 8);
        asm volatile("s_waitcnt vmcnt(0)" ::: "memory");
        __syncthreads();

        bf16x8 av[4], bv[4];
        #pragma unroll
        for (int i = 0; i < 4; i++)
            av[i] = *(const bf16x8*)&As[(wr * 64 + i * 16 + l16) * 32 + quad * 8];
        #pragma unroll
        for (int j = 0; j < 4; j++)
            bv[j] = *(const bf16x8*)&Bs[(wc * 64 + j * 16 + l16) * 32 + quad * 8];
        #pragma unroll
        for (int i = 0; i < 4; i++)
            #pragma unroll
            for (int j = 0; j < 4; j++)
                acc[i][j] = __builtin_amdgcn_mfma_f32_16x16x32_bf16(av[i], bv[j], acc[i][j], 0, 0, 0);
        __syncthreads();
    }

    #pragma unroll
    for (int i = 0; i < 4; i++) {
        int rbase = bm * 128 + wr * 64 + i * 16 + quad * 4;
        #pragma unroll
        for (int j = 0; j < 4; j++) {
            int col = bn * 128 + wc * 64 + j * 16 + l16;
            #pragma unroll
            for (int r = 0; r < 4; r++) {
                int row = rbase + r;
                float val = acc[i][j][r];
                if (MODE == 1) {
                    val += bias[col];
                    ((unsigned short*)Out)[(size_t)row * ldout + col] = f2b(val);
                } else {
                    ((float*)Out)[kz * pstride + (size_t)row * ldout + col] = val;
                }
            }
        }
    }
}

// ---------- sparsemax + gating: one WAVE per row, zero barriers ----------
__global__ __launch_bounds__(256)
void k_sparsemax(const unsigned short* __restrict__ a,
                 const unsigned short* __restrict__ xb,
                 unsigned short* __restrict__ wout) {
    const int wave = threadIdx.x >> 6;
    const int lane = threadIdx.x & 63;
    const int row = blockIdx.x * 4 + wave;

    const u16x8* ar = (const u16x8*)(a + (size_t)row * 4096);
    float v[64];
    #pragma unroll
    for (int j = 0; j < 8; j++) {
        u16x8 u = ar[lane + 64 * j];
        #pragma unroll
        for (int k = 0; k < 8; k++) v[j * 8 + k] = b2f(u[k]);
    }

    float m = v[0];
    #pragma unroll
    for (int i = 1; i < 64; i++) m = fmaxf(m, v[i]);
    #pragma unroll
    for (int off = 1; off < 64; off <<= 1) m = fmaxf(m, __shfl_xor(m, off));

    float lo = m - 1.0f, hi = m;
    #pragma unroll 1
    for (int it = 0; it < 18; ++it) {
        float mid = 0.5f * (lo + hi);
        float s = 0.f;
        #pragma unroll
        for (int i = 0; i < 64; i++) s += fmaxf(v[i] - mid, 0.f);
        #pragma unroll
        for (int off = 1; off < 64; off <<= 1) s += __shfl_xor(s, off);
        if (s > 1.0f) lo = mid; else hi = mid;
    }
    float tau = 0.5f * (lo + hi);

    const u16x8* xr = (const u16x8*)(xb + (size_t)row * 4096);
    u16x8* wr_ = (u16x8*)(wout + (size_t)row * 4096);
    #pragma unroll
    for (int j = 0; j < 8; j++) {
        u16x8 xv = xr[lane + 64 * j];
        u16x8 o;
        #pragma unroll
        for (int k = 0; k < 8; k++)
            o[k] = f2b(fmaxf(v[j * 8 + k] - tau, 0.f) * b2f(xv[k]));
        wr_[lane + 64 * j] = o;
    }
}

// ---------- final: out = relu(sum_p P[p] + bc1) @ Wc2 + bc2 ----------
__global__ __launch_bounds__(256)
void k_final(const float* __restrict__ P, const float* __restrict__ bc1,
             const float* __restrict__ Wc2, const float* __restrict__ bc2,
             float* __restrict__ out) {
    __shared__ float w2s[128 * 16];
    __shared__ float hs[4 * 128];
    const int tid = threadIdx.x;
    for (int i = tid; i < 2048; i += 256) w2s[i] = Wc2[i];

    #pragma unroll
    for (int i = tid; i < 512; i += 256) {
        int r = i >> 7, c = i & 127;
        int row = blockIdx.x * 4 + r;
        float s = bc1[c];
        #pragma unroll
        for (int p = 0; p < 8; p++)
            s += P[((size_t)p * 8192 + row) * 128 + c];
        hs[i] = fmaxf(s, 0.f);
    }
    __syncthreads();

    const int wave = tid >> 6, lane = tid & 63;
    const int row = blockIdx.x * 4 + wave;
    const int c = lane & 15, hq = lane >> 4;
    float acc = 0.f;
    #pragma unroll
    for (int t = 0; t < 32; ++t) {
        int hidx = hq * 32 + t;
        acc += hs[wave * 128 + hidx] * w2s[hidx * 16 + c];
    }
    acc += __shfl_xor(acc, 16);
    acc += __shfl_xor(acc, 32);
    if (hq == 0) out[(size_t)row * 16 + c] = acc + bc2[c];
}

// ---------- launch ----------

extern "C" void kernel_launch(void* const* d_in, const int* in_sizes, int n_in,
                              void* d_out, int out_size, void* d_ws, size_t ws_size,
                              hipStream_t stream) {
    (void)in_sizes; (void)n_in; (void)out_size; (void)ws_size;
    const float* x   = (const float*)d_in[0];
    const float* W1  = (const float*)d_in[1];
    const float* b1  = (const float*)d_in[2];
    const float* W2  = (const float*)d_in[3];
    const float* b2  = (const float*)d_in[4];
    const float* Wc1 = (const float*)d_in[5];
    const float* bc1 = (const float*)d_in[6];
    const float* Wc2 = (const float*)d_in[7];
    const float* bc2 = (const float*)d_in[8];
    float* out = (float*)d_out;

    char* ws = (char*)d_ws;
    unsigned short* xb   = (unsigned short*)(ws);                  // 0..64 MB  bf16 x (later: weighted)
    unsigned short* W1t  = (unsigned short*)(ws + (64ll  << 20));  // 64..72
    unsigned short* Tb   = (unsigned short*)(ws + (72ll  << 20));  // 72..88
    unsigned short* W2t  = (unsigned short*)(ws + (88ll  << 20));  // 88..96
    unsigned short* abf  = (unsigned short*)(ws + (96ll  << 20));  // 96..160  a bf16
    float*          P3   = (float*)         (ws + (96ll  << 20));  // 96..128  GEMM3 partials (after abf dead)
    unsigned short* Wc1t = (unsigned short*)(ws + (160ll << 20));  // 160..161
    unsigned short* wb   = xb;

    dim3 tb(32, 8);
    k_cvt<<<32768, 256, 0, stream>>>(x, xb);
    k_transpose_cvt<<<dim3(1024 / 32, 4096 / 32), tb, 0, stream>>>(W1, W1t, 4096, 1024);
    k_transpose_cvt<<<dim3(4096 / 32, 1024 / 32), tb, 0, stream>>>(W2, W2t, 1024, 4096);
    k_transpose_cvt<<<dim3(128 / 32, 4096 / 32), tb, 0, stream>>>(Wc1, Wc1t, 4096, 128);

    // T = tanh(x @ W1 + b1)  [8192][1024] bf16 — XCD-swizzled
    k_gemm_tanh<<<512, 512, 0, stream>>>(xb, W1t, b1, Tb, 1024, 4096, 4096, 4096);
    // a = T @ W2 + b2  [8192][4096] bf16 — XCD-swizzled (32 bn tiles -> LBN=5)
    k_gemm<1, 5><<<2048, 256, 0, stream>>>(Tb, W2t, b2, abf, 4096, 1024, 1024, 1024, 0);
    // weighted = x * sparsemax(a) -> bf16 (in place over xb)
    k_sparsemax<<<2048, 256, 0, stream>>>(abf, xb, wb);
    // GEMM3 split-K=8: P3[kz] = weighted @ Wc1 (unique reads; no swizzle needed)
    k_gemm<2, -1><<<dim3(1, 64, 8), 256, 0, stream>>>(wb, Wc1t, nullptr, P3, 128,
                                                      4096, 4096, 512, (size_t)8192 * 128);
    // out = relu(sum P3 + bc1) @ Wc2 + bc2
    k_final<<<2048, 256, 0, stream>>>(P3, bc1, Wc2, bc2, out);
}

// Round 5
// 436.137 us; speedup vs baseline: 1.2422x; 1.1249x over previous
//
#include <hip/hip_runtime.h>
#include <cstdint>

// ---------- common helpers ----------

typedef __bf16 bf16x8 __attribute__((ext_vector_type(8)));
typedef float  f32x4  __attribute__((ext_vector_type(4)));
typedef unsigned short u16x8 __attribute__((ext_vector_type(8)));

__device__ __forceinline__ unsigned short f2b(float f) {
    union { float f; unsigned u; } v; v.f = f;
    unsigned r = v.u + 0x7FFFu + ((v.u >> 16) & 1u);   // RNE
    return (unsigned short)(r >> 16);
}

__device__ __forceinline__ float b2f(unsigned short u) {
    union { unsigned u; float f; } v; v.u = ((unsigned)u) << 16;
    return v.f;
}

__device__ __forceinline__ float fast_tanh(float x) {
    // tanh(x) = 1 - 2/(e^{2x}+1); e^{2x} = 2^(x*2*log2 e). err ~1e-6 << bf16 eps
    float e = __builtin_amdgcn_exp2f(2.885390082f * x);
    return 1.0f - 2.0f * __builtin_amdgcn_rcpf(e + 1.0f);
}

__device__ __forceinline__ void async_copy16(void* lds, const void* g) {
    __builtin_amdgcn_global_load_lds(
        (const __attribute__((address_space(1))) unsigned int*)g,
        (__attribute__((address_space(3))) unsigned int*)lds,
        16, 0, 0);
}

// LDS layout (BK=64): tile 128 rows x 64 bf16 (128 B = 8 x 16B chunks per row).
// Slot q (linear 16B chunks) holds global chunk (r=q>>3, c=(q&7)^(r&7)).
// => global chunk (r,c) lives at elem offset r*64 + ((c^(r&7))<<3).
// ds_read banks: addr/4 = 32r + 4(c^(r&7)) -> 2-way max (free, m136).

// ---------- conversion kernels ----------

__global__ __launch_bounds__(256) void k_cvt(const float* __restrict__ in,
                                             unsigned short* __restrict__ out) {
    int i = blockIdx.x * 256 + threadIdx.x;
    float4 f = ((const float4*)in)[i];
    ushort4 o = make_ushort4(f2b(f.x), f2b(f.y), f2b(f.z), f2b(f.w));
    ((ushort4*)out)[i] = o;
}

// in: [R][C] fp32 row-major  ->  out: [C][R] bf16 (transposed)
__global__ __launch_bounds__(256) void k_transpose_cvt(const float* __restrict__ in,
                                                       unsigned short* __restrict__ out,
                                                       int R, int C) {
    __shared__ float tile[32][33];
    int bc = blockIdx.x * 32;
    int br = blockIdx.y * 32;
    int tx = threadIdx.x, ty = threadIdx.y;   // (32, 8)
    #pragma unroll
    for (int i = 0; i < 32; i += 8)
        tile[ty + i][tx] = in[(size_t)(br + ty + i) * C + bc + tx];
    __syncthreads();
    #pragma unroll
    for (int i = 0; i < 32; i += 8)
        out[(size_t)(bc + ty + i) * R + br + tx] = f2b(tile[tx][ty + i]);
}

// ---------- GEMM1: 512-thread 128x128 tile, BK=64, bias+tanh -> bf16 ----------
// XCD-swizzled 1-D grid: bm % 8 == xcd. 8 waves, wave tile 64x32.

__global__ __launch_bounds__(512, 4)
void k_gemm_tanh(const unsigned short* __restrict__ A,
                 const unsigned short* __restrict__ B,
                 const float* __restrict__ bias,
                 unsigned short* __restrict__ Out, int ldout,
                 int lda, int ldb, int k_len) {
    __shared__ __align__(16) unsigned short As[128 * 64];
    __shared__ __align__(16) unsigned short Bs[128 * 64];

    const int tid  = threadIdx.x;
    const int wave = tid >> 6;      // 0..7
    const int lane = tid & 63;
    const int quad = lane >> 4;
    const int l16  = lane & 15;
    const int wr   = wave >> 2;     // 0..1 : 64-row half
    const int wc   = wave & 3;      // 0..3 : 32-col quarter

    const int bid = blockIdx.x;
    const int xcd = bid & 7;
    const int lid = bid >> 3;
    const int bn  = lid & 7;
    const int bm  = (lid >> 3) * 8 + xcd;

    const unsigned short* Ag = A + (size_t)(bm * 128) * lda;
    const unsigned short* Bg = B + (size_t)(bn * 128) * ldb;

    f32x4 acc[4][2];
    #pragma unroll
    for (int i = 0; i < 4; i++)
        #pragma unroll
        for (int j = 0; j < 2; j++)
            acc[i][j] = f32x4{0.f, 0.f, 0.f, 0.f};

    // staging: 1024 chunks per matrix, 512 threads -> 2 issues each
    int sr[2], sc[2];
    #pragma unroll
    for (int j = 0; j < 2; j++) {
        int q = j * 512 + wave * 64 + lane;
        sr[j] = q >> 3;
        sc[j] = ((q & 7) ^ (sr[j] & 7)) << 3;   // element offset of source chunk
    }

    // fragment read offsets (loop-invariant)
    int roA[4], coA[4], roB[2], coB[2];
    #pragma unroll
    for (int i = 0; i < 4; i++) {
        int r = wr * 64 + i * 16 + l16;
        roA[i] = r * 64; coA[i] = quad ^ (r & 7);
    }
    #pragma unroll
    for (int j = 0; j < 2; j++) {
        int r = wc * 32 + j * 16 + l16;
        roB[j] = r * 64; coB[j] = quad ^ (r & 7);
    }

    for (int k0 = 0; k0 < k_len; k0 += 64) {
        #pragma unroll
        for (int j = 0; j < 2; j++) {
            async_copy16(&As[(j * 512 + wave * 64) * 8], Ag + (size_t)sr[j] * lda + k0 + sc[j]);
            async_copy16(&Bs[(j * 512 + wave * 64) * 8], Bg + (size_t)sr[j] * ldb + k0 + sc[j]);
        }
        asm volatile("s_waitcnt vmcnt(0)" ::: "memory");
        __syncthreads();

        #pragma unroll
        for (int s = 0; s < 2; s++) {
            bf16x8 av[4], bv[2];
            #pragma unroll
            for (int i = 0; i < 4; i++)
                av[i] = *(const bf16x8*)&As[roA[i] + ((coA[i] ^ (s << 2)) << 3)];
            #pragma unroll
            for (int j = 0; j < 2; j++)
                bv[j] = *(const bf16x8*)&Bs[roB[j] + ((coB[j] ^ (s << 2)) << 3)];
            #pragma unroll
            for (int i = 0; i < 4; i++)
                #pragma unroll
                for (int j = 0; j < 2; j++)
                    acc[i][j] = __builtin_amdgcn_mfma_f32_16x16x32_bf16(av[i], bv[j], acc[i][j], 0, 0, 0);
        }
        __syncthreads();
    }

    #pragma unroll
    for (int i = 0; i < 4; i++) {
        int rbase = bm * 128 + wr * 64 + i * 16 + quad * 4;
        #pragma unroll
        for (int j = 0; j < 2; j++) {
            int col = bn * 128 + wc * 32 + j * 16 + l16;
            float bc = bias[col];
            #pragma unroll
            for (int r = 0; r < 4; r++)
                Out[(size_t)(rbase + r) * ldout + col] = f2b(fast_tanh(acc[i][j][r] + bc));
        }
    }
}

// ---------- 256-thread 128x128 GEMM, BK=64 ----------
// MODE 1: +bias, store bf16, XCD-swizzled 1-D grid (LBN = log2(#bn tiles))
// MODE 2: store fp32 partial at Out + kz*pstride (split-K, 3-D grid)

template <int MODE, int LBN>
__global__ __launch_bounds__(256, 3)
void k_gemm(const unsigned short* __restrict__ A,
            const unsigned short* __restrict__ B,
            const float* __restrict__ bias,
            void* __restrict__ Out, int ldout,
            int lda, int ldb, int k_len, size_t pstride) {
    __shared__ __align__(16) unsigned short As[128 * 64];
    __shared__ __align__(16) unsigned short Bs[128 * 64];

    const int tid  = threadIdx.x;
    const int wave = tid >> 6;
    const int lane = tid & 63;
    const int quad = lane >> 4;
    const int l16  = lane & 15;
    const int wr   = wave >> 1;
    const int wc   = wave & 1;

    int bn, bm, kz;
    if (LBN >= 0) {
        const int bid = blockIdx.x;
        const int xcd = bid & 7;
        const int lid = bid >> 3;
        bn = lid & ((1 << LBN) - 1);
        bm = (lid >> LBN) * 8 + xcd;    // bm % 8 == xcd
        kz = 0;
    } else {
        bn = blockIdx.x; bm = blockIdx.y; kz = blockIdx.z;
    }

    const unsigned short* Ag = A + (size_t)(bm * 128) * lda + (size_t)kz * k_len;
    const unsigned short* Bg = B + (size_t)(bn * 128) * ldb + (size_t)kz * k_len;

    f32x4 acc[4][4];
    #pragma unroll
    for (int i = 0; i < 4; i++)
        #pragma unroll
        for (int j = 0; j < 4; j++)
            acc[i][j] = f32x4{0.f, 0.f, 0.f, 0.f};

    // staging: 1024 chunks per matrix, 256 threads -> 4 issues each
    int sr[4], sc[4];
    #pragma unroll
    for (int j = 0; j < 4; j++) {
        int q = j * 256 + wave * 64 + lane;
        sr[j] = q >> 3;
        sc[j] = ((q & 7) ^ (sr[j] & 7)) << 3;
    }

    int roA[4], coA[4], roB[4], coB[4];
    #pragma unroll
    for (int i = 0; i < 4; i++) {
        int ra = wr * 64 + i * 16 + l16;
        roA[i] = ra * 64; coA[i] = quad ^ (ra & 7);
        int rb = wc * 64 + i * 16 + l16;
        roB[i] = rb * 64; coB[i] = quad ^ (rb & 7);
    }

    for (int k0 = 0; k0 < k_len; k0 += 64) {
        #pragma unroll
        for (int j = 0; j < 4; j++) {
            async_copy16(&As[(j * 256 + wave * 64) * 8], Ag + (size_t)sr[j] * lda + k0 + sc[j]);
            async_copy16(&Bs[(j * 256 + wave * 64) * 8], Bg + (size_t)sr[j] * ldb + k0 + sc[j]);
        }
        asm volatile("s_waitcnt vmcnt(0)" ::: "memory");
        __syncthreads();

        #pragma unroll
        for (int s = 0; s < 2; s++) {
            bf16x8 av[4], bv[4];
            #pragma unroll
            for (int i = 0; i < 4; i++)
                av[i] = *(const bf16x8*)&As[roA[i] + ((coA[i] ^ (s << 2)) << 3)];
            #pragma unroll
            for (int j = 0; j < 4; j++)
                bv[j] = *(const bf16x8*)&Bs[roB[j] + ((coB[j] ^ (s << 2)) << 3)];
            #pragma unroll
            for (int i = 0; i < 4; i++)
                #pragma unroll
                for (int j = 0; j < 4; j++)
                    acc[i][j] = __builtin_amdgcn_mfma_f32_16x16x32_bf16(av[i], bv[j], acc[i][j], 0, 0, 0);
        }
        __syncthreads();
    }

    #pragma unroll
    for (int i = 0; i < 4; i++) {
        int rbase = bm * 128 + wr * 64 + i * 16 + quad * 4;
        #pragma unroll
        for (int j = 0; j < 4; j++) {
            int col = bn * 128 + wc * 64 + j * 16 + l16;
            #pragma unroll
            for (int r = 0; r < 4; r++) {
                int row = rbase + r;
                float val = acc[i][j][r];
                if (MODE == 1) {
                    val += bias[col];
                    ((unsigned short*)Out)[(size_t)row * ldout + col] = f2b(val);
                } else {
                    ((float*)Out)[kz * pstride + (size_t)row * ldout + col] = val;
                }
            }
        }
    }
}

// ---------- sparsemax + gating: one WAVE per row, zero barriers ----------
__global__ __launch_bounds__(256)
void k_sparsemax(const unsigned short* __restrict__ a,
                 const unsigned short* __restrict__ xb,
                 unsigned short* __restrict__ wout) {
    const int wave = threadIdx.x >> 6;
    const int lane = threadIdx.x & 63;
    const int row = blockIdx.x * 4 + wave;

    const u16x8* ar = (const u16x8*)(a + (size_t)row * 4096);
    float v[64];
    #pragma unroll
    for (int j = 0; j < 8; j++) {
        u16x8 u = ar[lane + 64 * j];
        #pragma unroll
        for (int k = 0; k < 8; k++) v[j * 8 + k] = b2f(u[k]);
    }

    float m = v[0];
    #pragma unroll
    for (int i = 1; i < 64; i++) m = fmaxf(m, v[i]);
    #pragma unroll
    for (int off = 1; off < 64; off <<= 1) m = fmaxf(m, __shfl_xor(m, off));

    float lo = m - 1.0f, hi = m;
    #pragma unroll 1
    for (int it = 0; it < 14; ++it) {
        float mid = 0.5f * (lo + hi);
        float s = 0.f;
        #pragma unroll
        for (int i = 0; i < 64; i++) s += fmaxf(v[i] - mid, 0.f);
        #pragma unroll
        for (int off = 1; off < 64; off <<= 1) s += __shfl_xor(s, off);
        if (s > 1.0f) lo = mid; else hi = mid;
    }
    float tau = 0.5f * (lo + hi);

    const u16x8* xr = (const u16x8*)(xb + (size_t)row * 4096);
    u16x8* wr_ = (u16x8*)(wout + (size_t)row * 4096);
    #pragma unroll
    for (int j = 0; j < 8; j++) {
        u16x8 xv = xr[lane + 64 * j];
        u16x8 o;
        #pragma unroll
        for (int k = 0; k < 8; k++)
            o[k] = f2b(fmaxf(v[j * 8 + k] - tau, 0.f) * b2f(xv[k]));
        wr_[lane + 64 * j] = o;
    }
}

// ---------- final: out = relu(sum_p P[p] + bc1) @ Wc2 + bc2 ----------
__global__ __launch_bounds__(256)
void k_final(const float* __restrict__ P, const float* __restrict__ bc1,
             const float* __restrict__ Wc2, const float* __restrict__ bc2,
             float* __restrict__ out) {
    __shared__ float w2s[128 * 16];
    __shared__ float hs[4 * 128];
    const int tid = threadIdx.x;
    for (int i = tid; i < 2048; i += 256) w2s[i] = Wc2[i];

    #pragma unroll
    for (int i = tid; i < 512; i += 256) {
        int r = i >> 7, c = i & 127;
        int row = blockIdx.x * 4 + r;
        float s = bc1[c];
        #pragma unroll
        for (int p = 0; p < 8; p++)
            s += P[((size_t)p * 8192 + row) * 128 + c];
        hs[i] = fmaxf(s, 0.f);
    }
    __syncthreads();

    const int wave = tid >> 6, lane = tid & 63;
    const int row = blockIdx.x * 4 + wave;
    const int c = lane & 15, hq = lane >> 4;
    float acc = 0.f;
    #pragma unroll
    for (int t = 0; t < 32; ++t) {
        int hidx = hq * 32 + t;
        acc += hs[wave * 128 + hidx] * w2s[hidx * 16 + c];
    }
    acc += __shfl_xor(acc, 16);
    acc += __shfl_xor(acc, 32);
    if (hq == 0) out[(size_t)row * 16 + c] = acc + bc2[c];
}

// ---------- launch ----------

extern "C" void kernel_launch(void* const* d_in, const int* in_sizes, int n_in,
                              void* d_out, int out_size, void* d_ws, size_t ws_size,
                              hipStream_t stream) {
    (void)in_sizes; (void)n_in; (void)out_size; (void)ws_size;
    const float* x   = (const float*)d_in[0];
    const float* W1  = (const float*)d_in[1];
    const float* b1  = (const float*)d_in[2];
    const float* W2  = (const float*)d_in[3];
    const float* b2  = (const float*)d_in[4];
    const float* Wc1 = (const float*)d_in[5];
    const float* bc1 = (const float*)d_in[6];
    const float* Wc2 = (const float*)d_in[7];
    const float* bc2 = (const float*)d_in[8];
    float* out = (float*)d_out;

    char* ws = (char*)d_ws;
    unsigned short* xb   = (unsigned short*)(ws);                  // 0..64 MB  bf16 x (later: weighted)
    unsigned short* W1t  = (unsigned short*)(ws + (64ll  << 20));  // 64..72
    unsigned short* Tb   = (unsigned short*)(ws + (72ll  << 20));  // 72..88
    unsigned short* W2t  = (unsigned short*)(ws + (88ll  << 20));  // 88..96
    unsigned short* abf  = (unsigned short*)(ws + (96ll  << 20));  // 96..160  a bf16
    float*          P3   = (float*)         (ws + (96ll  << 20));  // 96..128  GEMM3 partials (after abf dead)
    unsigned short* Wc1t = (unsigned short*)(ws + (160ll << 20));  // 160..161
    unsigned short* wb   = xb;

    dim3 tb(32, 8);
    k_cvt<<<32768, 256, 0, stream>>>(x, xb);
    k_transpose_cvt<<<dim3(1024 / 32, 4096 / 32), tb, 0, stream>>>(W1, W1t, 4096, 1024);
    k_transpose_cvt<<<dim3(4096 / 32, 1024 / 32), tb, 0, stream>>>(W2, W2t, 1024, 4096);
    k_transpose_cvt<<<dim3(128 / 32, 4096 / 32), tb, 0, stream>>>(Wc1, Wc1t, 4096, 128);

    // T = tanh(x @ W1 + b1)  [8192][1024] bf16 — XCD-swizzled, BK=64
    k_gemm_tanh<<<512, 512, 0, stream>>>(xb, W1t, b1, Tb, 1024, 4096, 4096, 4096);
    // a = T @ W2 + b2  [8192][4096] bf16 — XCD-swizzled (32 bn tiles -> LBN=5)
    k_gemm<1, 5><<<2048, 256, 0, stream>>>(Tb, W2t, b2, abf, 4096, 1024, 1024, 1024, 0);
    // weighted = x * sparsemax(a) -> bf16 (in place over xb)
    k_sparsemax<<<2048, 256, 0, stream>>>(abf, xb, wb);
    // GEMM3 split-K=8: P3[kz] = weighted @ Wc1 (unique reads; no swizzle needed)
    k_gemm<2, -1><<<dim3(1, 64, 8), 256, 0, stream>>>(wb, Wc1t, nullptr, P3, 128,
                                                      4096, 4096, 512, (size_t)8192 * 128);
    // out = relu(sum P3 + bc1) @ Wc2 + bc2
    k_final<<<2048, 256, 0, stream>>>(P3, bc1, Wc2, bc2, out);
}